// Round 1
// 1081.022 us; speedup vs baseline: 1.0604x; 1.0604x over previous
//
#include <hip/hip_runtime.h>

#define NB   8
#define CIN  1024
#define TT   4096
#define DVQ  1024
#define KC   2048
#define MM   16384

typedef short s16x8 __attribute__((ext_vector_type(8)));
typedef float f32x4 __attribute__((ext_vector_type(4)));

__device__ __forceinline__ short f2bf(float f) {
    unsigned u = __float_as_uint(f);
    u = u + 0x7fffu + ((u >> 16) & 1u);   // RNE
    return (short)(u >> 16);
}
__device__ __forceinline__ float bf2f(short h) {
    return __uint_as_float(((unsigned)(unsigned short)h) << 16);
}
__device__ __forceinline__ unsigned pk(short a, short b) {
    return (unsigned)(unsigned short)a | ((unsigned)(unsigned short)b << 16);
}
__device__ __forceinline__ void split3(float v, short& h, short& m, short& l) {
    h = f2bf(v); float r1 = v - bf2f(h);
    m = f2bf(r1); float r2 = r1 - bf2f(m);
    l = f2bf(r2);
}
// swizzled A-plane address (shorts): row-major, 40 shorts/row, 8-short blocks
// XOR-permuted by (row>>3)&3.  (legacy kernels)
__device__ __forceinline__ int aswz(int row, int q) {
    return row * 40 + (((q ^ (row >> 3)) & 3) << 3);
}
__device__ __forceinline__ bool lesskey(float v, int k, float v2, int k2) {
    return v < v2 || (v == v2 && k < k2);
}
__device__ __forceinline__ void merge2(float& b1, int& k1, float& b2, int& k2,
                                       float o1, int ok1, float o2, int ok2) {
    if (lesskey(o1, ok1, b1, k1)) {
        float nb2; int nk2;
        if (lesskey(b1, k1, o2, ok2)) { nb2 = b1; nk2 = k1; } else { nb2 = o2; nk2 = ok2; }
        b1 = o1; k1 = ok1; b2 = nb2; k2 = nk2;
    } else if (lesskey(o1, ok1, b2, k2)) {
        b2 = o1; k2 = ok1;
    }
}
// async 16B global->LDS copy (direct-to-shared DMA)
__device__ __forceinline__ void gload16(void* lds, const void* g) {
    __builtin_amdgcn_global_load_lds((const __attribute__((address_space(1))) void*)g,
                                     (__attribute__((address_space(3))) void*)lds, 16, 0, 0);
}

// ============================= preps =======================================
__global__ __launch_bounds__(256) void k_split3(const float* __restrict__ src,
                                                short* __restrict__ h, short* __restrict__ m,
                                                short* __restrict__ l, int n4) {
    int i = blockIdx.x * 256 + threadIdx.x;
    if (i >= n4) return;
    float4 v = ((const float4*)src)[i];
    short4 H, M, L;
    split3(v.x, H.x, M.x, L.x); split3(v.y, H.y, M.y, L.y);
    split3(v.z, H.z, M.z, L.z); split3(v.w, H.w, M.w, L.w);
    ((short4*)h)[i] = H; ((short4*)m)[i] = M; ((short4*)l)[i] = L;
}

__global__ __launch_bounds__(256) void k_split2(const float* __restrict__ src,
                                                short* __restrict__ h, short* __restrict__ l, int n4) {
    int i = blockIdx.x * 256 + threadIdx.x;
    if (i >= n4) return;
    float4 v = ((const float4*)src)[i];
    short4 H, L;
    H.x = f2bf(v.x); L.x = f2bf(v.x - bf2f(H.x));
    H.y = f2bf(v.y); L.y = f2bf(v.y - bf2f(H.y));
    H.z = f2bf(v.z); L.z = f2bf(v.z - bf2f(H.z));
    H.w = f2bf(v.w); L.w = f2bf(v.w - bf2f(H.w));
    ((short4*)h)[i] = H; ((short4*)l)[i] = L;
}

__global__ __launch_bounds__(256) void k_cnorm(const float* __restrict__ cb,
                                               float* __restrict__ c32,
                                               double* __restrict__ c64) {
    __shared__ double red[256];
    const float* row = cb + (size_t)blockIdx.x * DVQ;
    float4 v = ((const float4*)row)[threadIdx.x];
    red[threadIdx.x] = (double)v.x * v.x + (double)v.y * v.y +
                       (double)v.z * v.z + (double)v.w * v.w;
    __syncthreads();
    for (int o = 128; o > 0; o >>= 1) {
        if (threadIdx.x < o) red[threadIdx.x] += red[threadIdx.x + o];
        __syncthreads();
    }
    if (threadIdx.x == 0) { c64[blockIdx.x] = red[0]; c32[blockIdx.x] = (float)red[0]; }
}

// ============ A-plane materialization: transpose + 3-way RNE split =========
// x[b][c][T] f32  ->  Ah/Am/Al[m = b*2048+t][k = 2c+s]  (bf16 planes)
// Each thread owns one channel c, loops t; reads 16B/step (L1 line reuse),
// writes one u32 (k-pair 2c,2c+1) per plane per row -> lanes consecutive in c
// => 256B coalesced stores.  Values are bit-identical to the legacy in-loop
// split3, so xt stays bit-identical to the previous kernel.
__global__ __launch_bounds__(256) void k_asplit(const float* __restrict__ x,
                                                short* __restrict__ ah,
                                                short* __restrict__ am,
                                                short* __restrict__ al) {
    const int bid = blockIdx.x;
    const int b = bid >> 7, cblk = (bid >> 5) & 3, tch = bid & 31;
    const int c = cblk * 256 + threadIdx.x;
    const float* xr = x + ((size_t)b * CIN + c) * TT + tch * 128;
    unsigned* AH = (unsigned*)ah;
    unsigned* AM = (unsigned*)am;
    unsigned* AL = (unsigned*)al;
    const int mbase = b * 2048 + tch * 64;
#pragma unroll 4
    for (int i = 0; i < 32; ++i) {
        float4 v = *(const float4*)(xr + 4 * i);
        short h0, mm0, l0, h1, mm1, l1, h2, mm2, l2, h3, mm3, l3;
        split3(v.x, h0, mm0, l0); split3(v.y, h1, mm1, l1);
        split3(v.z, h2, mm2, l2); split3(v.w, h3, mm3, l3);
        const size_t o0 = (size_t)(mbase + 2 * i) * 1024 + c;
        const size_t o1 = o0 + 1024;
        AH[o0] = pk(h0, h1); AM[o0] = pk(mm0, mm1); AL[o0] = pk(l0, l1);
        AH[o1] = pk(h2, h3); AM[o1] = pk(mm2, mm3); AL[o1] = pk(l2, l3);
    }
}

// ======== conv-in GEMM from materialized planes (fast path) ================
// 128x128 tile, BK=32, 4 waves (2x2), wave tile 64x64.  global_load_lds 16B
// staging into linear [row][32] LDS (row stride 64B + quad*16B => b128 reads
// spread over all 8 bank-groups, conflict-free).  Same 6 products per acc in
// the same order + same K=64 chunk flush as the legacy kernel => bit-identical.
__global__ __launch_bounds__(256, 2) void k_convp(const short* __restrict__ ah,
                                                  const short* __restrict__ am,
                                                  const short* __restrict__ al,
                                                  const short* __restrict__ wh,
                                                  const short* __restrict__ wm,
                                                  const short* __restrict__ wl,
                                                  const float* __restrict__ bias,
                                                  float* __restrict__ xt,
                                                  short* __restrict__ xth,
                                                  short* __restrict__ xtl) {
    __shared__ short s[6][128 * 32];   // Ah Am Al Bh Bm Bl : 48 KiB
    const int tid = threadIdx.x;
    // XCD-aware remap: XCD cx owns 16 consecutive m-tiles x all 8 n-tiles
    const int lin = blockIdx.x;
    const int cx = lin & 7, j = lin >> 3;
    const int m0 = (cx * 16 + (j >> 3)) * 128;
    const int n0 = (j & 7) * 128;

    const int wv = tid >> 6, lane = tid & 63;
    const int slot0 = wv * 128 + lane, slot1 = slot0 + 64;   // 512 slots/plane
    const int row0 = slot0 >> 2, c80 = (slot0 & 3) * 8;
    const int row1 = slot1 >> 2, c81 = (slot1 & 3) * 8;
    const size_t ga0 = (size_t)(m0 + row0) * 2048 + c80;
    const size_t ga1 = (size_t)(m0 + row1) * 2048 + c81;
    const size_t gb0 = (size_t)(n0 + row0) * 2048 + c80;
    const size_t gb1 = (size_t)(n0 + row1) * 2048 + c81;

    const int ln = tid & 15, quad = (tid >> 4) & 3;
    const int r0w = (wv >> 1) * 64, c0w = (wv & 1) * 64;

    f32x4 acc[4][4], sums[4][4];
#pragma unroll
    for (int r = 0; r < 4; ++r)
#pragma unroll
        for (int c = 0; c < 4; ++c) { acc[r][c] = 0.f; sums[r][c] = 0.f; }

#pragma unroll 2
    for (int it = 0; it < 64; ++it) {
        const int k0 = it * 32;
        __syncthreads();                       // prior reads of buffer done
        gload16(&s[0][slot0 * 8], ah + ga0 + k0);
        gload16(&s[0][slot1 * 8], ah + ga1 + k0);
        gload16(&s[1][slot0 * 8], am + ga0 + k0);
        gload16(&s[1][slot1 * 8], am + ga1 + k0);
        gload16(&s[2][slot0 * 8], al + ga0 + k0);
        gload16(&s[2][slot1 * 8], al + ga1 + k0);
        gload16(&s[3][slot0 * 8], wh + gb0 + k0);
        gload16(&s[3][slot1 * 8], wh + gb1 + k0);
        gload16(&s[4][slot0 * 8], wm + gb0 + k0);
        gload16(&s[4][slot1 * 8], wm + gb1 + k0);
        gload16(&s[5][slot0 * 8], wl + gb0 + k0);
        gload16(&s[5][slot1 * 8], wl + gb1 + k0);
        __syncthreads();                       // vmcnt(0) drain + barrier

        s16x8 fa0[4], fa1[4], fa2[4];          // hold A frags, stream B
#pragma unroll
        for (int r = 0; r < 4; ++r) {
            const int off = (r0w + r * 16 + ln) * 32 + quad * 8;
            fa0[r] = *(const s16x8*)&s[0][off];
            fa1[r] = *(const s16x8*)&s[1][off];
            fa2[r] = *(const s16x8*)&s[2][off];
        }
#pragma unroll
        for (int c = 0; c < 4; ++c) {
            const int boff = (c0w + c * 16 + ln) * 32 + quad * 8;
            s16x8 fbh = *(const s16x8*)&s[3][boff];
            s16x8 fbm = *(const s16x8*)&s[4][boff];
            s16x8 fbl = *(const s16x8*)&s[5][boff];
#pragma unroll
            for (int r = 0; r < 4; ++r) {
                acc[r][c] = __builtin_amdgcn_mfma_f32_16x16x32_bf16(fa0[r], fbh, acc[r][c], 0, 0, 0);
                acc[r][c] = __builtin_amdgcn_mfma_f32_16x16x32_bf16(fa0[r], fbm, acc[r][c], 0, 0, 0);
                acc[r][c] = __builtin_amdgcn_mfma_f32_16x16x32_bf16(fa1[r], fbh, acc[r][c], 0, 0, 0);
                acc[r][c] = __builtin_amdgcn_mfma_f32_16x16x32_bf16(fa0[r], fbl, acc[r][c], 0, 0, 0);
                acc[r][c] = __builtin_amdgcn_mfma_f32_16x16x32_bf16(fa1[r], fbm, acc[r][c], 0, 0, 0);
                acc[r][c] = __builtin_amdgcn_mfma_f32_16x16x32_bf16(fa2[r], fbh, acc[r][c], 0, 0, 0);
            }
        }
        if (it & 1) {   // chunk flush (K=64) — identical to legacy
#pragma unroll
            for (int r = 0; r < 4; ++r)
#pragma unroll
                for (int c = 0; c < 4; ++c) { sums[r][c] += acc[r][c]; acc[r][c] = 0.f; }
        }
    }
#pragma unroll
    for (int c = 0; c < 4; ++c) {
        const int n = n0 + c0w + c * 16 + ln;
        const float bv = bias[n];
#pragma unroll
        for (int r = 0; r < 4; ++r)
#pragma unroll
            for (int g = 0; g < 4; ++g) {
                const int m = m0 + r0w + r * 16 + quad * 4 + g;
                const float v = sums[r][c][g] + bv;
                const size_t o = (size_t)m * DVQ + n;
                xt[o] = v;
                short h = f2bf(v);
                xth[o] = h;
                xtl[o] = f2bf(v - bf2f(h));
            }
    }
}

// ======== conv-in GEMM: legacy in-kernel split (ws fallback) ===============
__global__ __launch_bounds__(256, 2) void k_conv(const float* __restrict__ x,
                                                 const short* __restrict__ wh,
                                                 const short* __restrict__ wm,
                                                 const short* __restrict__ wl,
                                                 const float* __restrict__ bias,
                                                 float* __restrict__ xt,
                                                 short* __restrict__ xth,
                                                 short* __restrict__ xtl) {
    __shared__ short sAh[128 * 40], sAm[128 * 40], sAl[128 * 40];
    __shared__ short sBh[64 * 40],  sBm[64 * 40],  sBl[64 * 40];
    const int tid = threadIdx.x;
    const int lin = blockIdx.x;
    const int cx = lin & 7, j = lin >> 3;
    const int m0 = (cx * 16 + (j >> 4)) * 128;
    const int n0 = (j & 15) * 64;
    const int b = m0 >> 11, t0 = m0 & 2047;
    const float* xb = x + (size_t)b * CIN * TT + 2 * t0;

    const int aw = tid >> 6, p = tid & 63;
    const int brow = tid >> 2, bq = tid & 3;
    const int ln = tid & 15, quad = (tid >> 4) & 3;
    const int r0 = (aw >> 1) * 64, c0 = (aw & 1) * 32;

    f32x4 acc[4][2], sums[4][2];
#pragma unroll
    for (int r = 0; r < 4; ++r)
#pragma unroll
        for (int c = 0; c < 2; ++c) { acc[r][c] = 0.f; sums[r][c] = 0.f; }

    float4 av[4];
    uint4 bh0, bm0, bl0;
#pragma unroll
    for (int r = 0; r < 4; ++r) av[r] = *(const float4*)(xb + (size_t)(4 * r + aw) * TT + 4 * p);
    {
        const size_t o = (size_t)(n0 + brow) * 2048 + bq * 8;
        bh0 = *(const uint4*)&wh[o]; bm0 = *(const uint4*)&wm[o]; bl0 = *(const uint4*)&wl[o];
    }

    for (int it = 0; it < 64; ++it) {
        __syncthreads();
#pragma unroll
        for (int r = 0; r < 4; ++r) {
            const int ii = r * 4 + aw;
            const int q = ii >> 2, off = (2 * ii) & 7;
            const int a0 = aswz(2 * p, q) + off;
            const int a1 = aswz(2 * p + 1, q) + off;
            float4 v = av[r];
            short hx, mx, lx, hy, my, ly;
            split3(v.x, hx, mx, lx); split3(v.y, hy, my, ly);
            *(unsigned*)&sAh[a0] = pk(hx, hy);
            *(unsigned*)&sAm[a0] = pk(mx, my);
            *(unsigned*)&sAl[a0] = pk(lx, ly);
            split3(v.z, hx, mx, lx); split3(v.w, hy, my, ly);
            *(unsigned*)&sAh[a1] = pk(hx, hy);
            *(unsigned*)&sAm[a1] = pk(mx, my);
            *(unsigned*)&sAl[a1] = pk(lx, ly);
        }
        {
            const int w0 = brow * 40 + bq * 8;
            *(uint4*)&sBh[w0] = bh0; *(uint4*)&sBm[w0] = bm0; *(uint4*)&sBl[w0] = bl0;
        }
        __syncthreads();
        if (it + 1 < 64) {
            const int i0 = (it + 1) * 16, k0 = (it + 1) * 32;
#pragma unroll
            for (int r = 0; r < 4; ++r)
                av[r] = *(const float4*)(xb + (size_t)(i0 + 4 * r + aw) * TT + 4 * p);
            const size_t o = (size_t)(n0 + brow) * 2048 + k0 + bq * 8;
            bh0 = *(const uint4*)&wh[o]; bm0 = *(const uint4*)&wm[o]; bl0 = *(const uint4*)&wl[o];
        }
        s16x8 fah[4], fam[4], fal[4];
#pragma unroll
        for (int r = 0; r < 4; ++r) {
            const int base = aswz(r0 + r * 16 + ln, quad);
            fah[r] = *(const s16x8*)&sAh[base];
            fam[r] = *(const s16x8*)&sAm[base];
            fal[r] = *(const s16x8*)&sAl[base];
        }
#pragma unroll
        for (int c = 0; c < 2; ++c) {
            const int bb = (c0 + c * 16 + ln) * 40 + quad * 8;
            s16x8 fbh = *(const s16x8*)&sBh[bb];
            s16x8 fbm = *(const s16x8*)&sBm[bb];
            s16x8 fbl = *(const s16x8*)&sBl[bb];
#pragma unroll
            for (int r = 0; r < 4; ++r) {
                acc[r][c] = __builtin_amdgcn_mfma_f32_16x16x32_bf16(fah[r], fbh, acc[r][c], 0, 0, 0);
                acc[r][c] = __builtin_amdgcn_mfma_f32_16x16x32_bf16(fah[r], fbm, acc[r][c], 0, 0, 0);
                acc[r][c] = __builtin_amdgcn_mfma_f32_16x16x32_bf16(fam[r], fbh, acc[r][c], 0, 0, 0);
                acc[r][c] = __builtin_amdgcn_mfma_f32_16x16x32_bf16(fah[r], fbl, acc[r][c], 0, 0, 0);
                acc[r][c] = __builtin_amdgcn_mfma_f32_16x16x32_bf16(fam[r], fbm, acc[r][c], 0, 0, 0);
                acc[r][c] = __builtin_amdgcn_mfma_f32_16x16x32_bf16(fal[r], fbh, acc[r][c], 0, 0, 0);
            }
        }
        if (it & 1) {
#pragma unroll
            for (int r = 0; r < 4; ++r)
#pragma unroll
                for (int c = 0; c < 2; ++c) { sums[r][c] += acc[r][c]; acc[r][c] = 0.f; }
        }
    }
#pragma unroll
    for (int c = 0; c < 2; ++c) {
        const int n = n0 + c0 + c * 16 + ln;
        const float bv = bias[n];
#pragma unroll
        for (int r = 0; r < 4; ++r)
#pragma unroll
            for (int g = 0; g < 4; ++g) {
                const int m = m0 + r0 + r * 16 + quad * 4 + g;
                const float v = sums[r][c][g] + bv;
                const size_t o = (size_t)m * DVQ + n;
                xt[o] = v;
                short h = f2bf(v);
                xth[o] = h;
                xtl[o] = f2bf(v - bf2f(h));
            }
    }
}

// ====== distance GEMM (2-plane planes from conv) + fused exact top-2 =======
__global__ __launch_bounds__(256, 2) void k_dot(const short* __restrict__ xth,
                                                const short* __restrict__ xtl,
                                                const short* __restrict__ cbh,
                                                const short* __restrict__ cbl,
                                                const float* __restrict__ c32,
                                                float4* __restrict__ pb) {
    __shared__ __align__(16) short sAh[128 * 40], sAl[128 * 40], sBh[128 * 40], sBl[128 * 40];
    const int tid = threadIdx.x;
    const int n0 = blockIdx.x * 128, m0 = blockIdx.y * 128;
    const int ar = tid >> 2, q = tid & 3, kk = q * 8;
    const int ln = tid & 15, quad = (tid >> 4) & 3, wv = tid >> 6;
    const int r0 = (wv >> 1) * 64, c0 = (wv & 1) * 64;

    f32x4 acc[4][4];
#pragma unroll
    for (int r = 0; r < 4; ++r)
#pragma unroll
        for (int c = 0; c < 4; ++c) acc[r][c] = 0.f;

    uint4 a0 = *(const uint4*)&xth[(size_t)(m0 + ar) * 1024 + kk];
    uint4 a1 = *(const uint4*)&xth[(size_t)(m0 + 64 + ar) * 1024 + kk];
    uint4 a2 = *(const uint4*)&xtl[(size_t)(m0 + ar) * 1024 + kk];
    uint4 a3 = *(const uint4*)&xtl[(size_t)(m0 + 64 + ar) * 1024 + kk];
    uint4 b0 = *(const uint4*)&cbh[(size_t)(n0 + ar) * 1024 + kk];
    uint4 b1 = *(const uint4*)&cbh[(size_t)(n0 + 64 + ar) * 1024 + kk];
    uint4 b2 = *(const uint4*)&cbl[(size_t)(n0 + ar) * 1024 + kk];
    uint4 b3 = *(const uint4*)&cbl[(size_t)(n0 + 64 + ar) * 1024 + kk];

    for (int it = 0; it < 32; ++it) {
        __syncthreads();
        *(uint4*)&sAh[aswz(ar, q)] = a0;
        *(uint4*)&sAh[aswz(64 + ar, q)] = a1;
        *(uint4*)&sAl[aswz(ar, q)] = a2;
        *(uint4*)&sAl[aswz(64 + ar, q)] = a3;
        {
            const int w0 = ar * 40 + kk, w1 = (64 + ar) * 40 + kk;
            *(uint4*)&sBh[w0] = b0; *(uint4*)&sBh[w1] = b1;
            *(uint4*)&sBl[w0] = b2; *(uint4*)&sBl[w1] = b3;
        }
        __syncthreads();
        if (it + 1 < 32) {
            const int k0 = (it + 1) * 32;
            a0 = *(const uint4*)&xth[(size_t)(m0 + ar) * 1024 + k0 + kk];
            a1 = *(const uint4*)&xth[(size_t)(m0 + 64 + ar) * 1024 + k0 + kk];
            a2 = *(const uint4*)&xtl[(size_t)(m0 + ar) * 1024 + k0 + kk];
            a3 = *(const uint4*)&xtl[(size_t)(m0 + 64 + ar) * 1024 + k0 + kk];
            b0 = *(const uint4*)&cbh[(size_t)(n0 + ar) * 1024 + k0 + kk];
            b1 = *(const uint4*)&cbh[(size_t)(n0 + 64 + ar) * 1024 + k0 + kk];
            b2 = *(const uint4*)&cbl[(size_t)(n0 + ar) * 1024 + k0 + kk];
            b3 = *(const uint4*)&cbl[(size_t)(n0 + 64 + ar) * 1024 + k0 + kk];
        }
        s16x8 fah[4], fal[4];
#pragma unroll
        for (int r = 0; r < 4; ++r) {
            const int base = aswz(r0 + r * 16 + ln, quad);
            fah[r] = *(const s16x8*)&sAh[base];
            fal[r] = *(const s16x8*)&sAl[base];
        }
#pragma unroll
        for (int c = 0; c < 4; ++c) {
            const int bb = (c0 + c * 16 + ln) * 40 + quad * 8;
            s16x8 fbh = *(const s16x8*)&sBh[bb];
            s16x8 fbl = *(const s16x8*)&sBl[bb];
#pragma unroll
            for (int r = 0; r < 4; ++r) {
                acc[r][c] = __builtin_amdgcn_mfma_f32_16x16x32_bf16(fah[r], fbh, acc[r][c], 0, 0, 0);
                acc[r][c] = __builtin_amdgcn_mfma_f32_16x16x32_bf16(fah[r], fbl, acc[r][c], 0, 0, 0);
                acc[r][c] = __builtin_amdgcn_mfma_f32_16x16x32_bf16(fal[r], fbh, acc[r][c], 0, 0, 0);
            }
        }
    }
    // per-thread top-2 (ascending n per row; strict < keeps first occurrence)
    float tb1[16], tb2[16]; int tk1[16], tk2[16];
#pragma unroll
    for (int i = 0; i < 16; ++i) { tb1[i] = INFINITY; tb2[i] = INFINITY; tk1[i] = 0; tk2[i] = 0; }
#pragma unroll
    for (int c = 0; c < 4; ++c) {
        const int n = n0 + c0 + c * 16 + ln;
        const float cn = c32[n];
#pragma unroll
        for (int r = 0; r < 4; ++r)
#pragma unroll
            for (int g = 0; g < 4; ++g) {
                const float s = cn - 2.0f * acc[r][c][g];
                const int i = r * 4 + g;
                if (s < tb1[i]) { tb2[i] = tb1[i]; tk2[i] = tk1[i]; tb1[i] = s; tk1[i] = n; }
                else if (s < tb2[i]) { tb2[i] = s; tk2[i] = n; }
            }
    }
    // lossless top-2 butterfly across the 16 ln-lanes
#pragma unroll
    for (int off = 1; off < 16; off <<= 1) {
#pragma unroll
        for (int i = 0; i < 16; ++i) {
            float o1 = __shfl_xor(tb1[i], off); int ok1 = __shfl_xor(tk1[i], off);
            float o2 = __shfl_xor(tb2[i], off); int ok2 = __shfl_xor(tk2[i], off);
            merge2(tb1[i], tk1[i], tb2[i], tk2[i], o1, ok1, o2, ok2);
        }
    }
    __syncthreads();
    float4* part = (float4*)sAh;   // 4 KB overlay
    if (ln == 0) {
#pragma unroll
        for (int i = 0; i < 16; ++i) {
            const int lr = (i >> 2) * 16 + quad * 4 + (i & 3);
            float4 v; v.x = tb1[i]; v.y = tb2[i];
            v.z = __int_as_float(tk1[i]); v.w = __int_as_float(tk2[i]);
            part[wv * 64 + lr] = v;
        }
    }
    __syncthreads();
    if (tid < 128) {
        const int row = tid, h = row >> 6, lr = row & 63;
        float4 A = part[(2 * h) * 64 + lr];
        float4 B = part[(2 * h + 1) * 64 + lr];
        float b1v = A.x, b2v = A.y; int k1 = __float_as_int(A.z), k2 = __float_as_int(A.w);
        merge2(b1v, k1, b2v, k2, B.x, __float_as_int(B.z), B.y, __float_as_int(B.w));
        float4 o; o.x = b1v; o.y = b2v; o.z = __int_as_float(k1); o.w = __int_as_float(k2);
        pb[(size_t)blockIdx.x * MM + m0 + row] = o;
    }
}

// ============ merge 16 strips + exact f64 rescore of top-2 =================
__global__ __launch_bounds__(256) void k_pick(const float4* __restrict__ pb,
                                              const double* __restrict__ c64,
                                              const float* __restrict__ xt,
                                              const float* __restrict__ cb,
                                              int* __restrict__ idxbuf,
                                              float* __restrict__ idx_out) {
    const int wv = threadIdx.x >> 6, lane = threadIdx.x & 63;
    const int m = blockIdx.x * 4 + wv;
    float4 P = pb[m];
    float b1 = P.x, b2 = P.y; int k1 = __float_as_int(P.z), k2 = __float_as_int(P.w);
#pragma unroll
    for (int s = 1; s < 16; ++s) {
        float4 Q = pb[(size_t)s * MM + m];
        merge2(b1, k1, b2, k2, Q.x, __float_as_int(Q.z), Q.y, __float_as_int(Q.w));
    }
    const float* xr = xt + (size_t)m * DVQ;
    const float* c1 = cb + (size_t)k1 * DVQ;
    const float* c2 = cb + (size_t)k2 * DVQ;
    double e1 = 0.0, e2 = 0.0;
    for (int j = 0; j < DVQ / 64; ++j) {
        const int d = j * 64 + lane;
        const double xv = xr[d];
        e1 += xv * (double)c1[d]; e2 += xv * (double)c2[d];
    }
    for (int off = 32; off > 0; off >>= 1) { e1 += __shfl_xor(e1, off); e2 += __shfl_xor(e2, off); }
    if (lane == 0) {
        const double s1 = c64[k1] - 2.0 * e1;
        const double s2 = c64[k2] - 2.0 * e2;
        const int kf = (s2 < s1 || (s2 == s1 && k2 < k1)) ? k2 : k1;
        idxbuf[m] = kf;
        idx_out[m] = (float)kf;
    }
}

// ================================= loss ====================================
__global__ __launch_bounds__(256) void k_losspart(const float* __restrict__ xt,
                                                  const float* __restrict__ cb,
                                                  const int* __restrict__ idxbuf,
                                                  float* __restrict__ partials) {
    __shared__ float red[256];
    const int m = blockIdx.x;
    const int row = idxbuf[m];
    float4 a = ((const float4*)(xt + (size_t)m * DVQ))[threadIdx.x];
    float4 c = ((const float4*)(cb + (size_t)row * DVQ))[threadIdx.x];
    const float dx = a.x - c.x, dy = a.y - c.y, dz = a.z - c.z, dw = a.w - c.w;
    red[threadIdx.x] = dx * dx + dy * dy + dz * dz + dw * dw;
    __syncthreads();
    for (int o = 128; o > 0; o >>= 1) {
        if (threadIdx.x < o) red[threadIdx.x] += red[threadIdx.x + o];
        __syncthreads();
    }
    if (threadIdx.x == 0) partials[m] = red[0];
}

__global__ __launch_bounds__(256) void k_lossfinal(const float* __restrict__ partials,
                                                   float* __restrict__ loss_out) {
    __shared__ float red[256];
    float s = 0.0f;
    for (int i = threadIdx.x; i < MM; i += 256) s += partials[i];
    red[threadIdx.x] = s;
    __syncthreads();
    for (int o = 128; o > 0; o >>= 1) {
        if (threadIdx.x < o) red[threadIdx.x] += red[threadIdx.x + o];
        __syncthreads();
    }
    if (threadIdx.x == 0) loss_out[0] = red[0] / (float)((size_t)MM * DVQ);
}

// ============== out projection (gathered codebook, 2-plane) ================
__global__ __launch_bounds__(256, 2) void k_out(const int* __restrict__ idxbuf,
                                                const short* __restrict__ ch,
                                                const short* __restrict__ cl,
                                                const short* __restrict__ wh,
                                                const short* __restrict__ wl,
                                                const float* __restrict__ bias,
                                                const float* __restrict__ xm,
                                                float* __restrict__ outp) {
    __shared__ short sAh[128 * 40], sAl[128 * 40], sBh[128 * 40], sBl[128 * 40];
    __shared__ int rows_s[128];
    const int tid = threadIdx.x;
    const int m0 = blockIdx.y * 128, n0 = blockIdx.x * 128;
    if (tid < 128) rows_s[tid] = idxbuf[m0 + tid];
    __syncthreads();
    const int ar = tid >> 2, q = tid & 3, kk = q * 8;
    const int ln = tid & 15, quad = (tid >> 4) & 3, wv = tid >> 6;
    const int r0 = (wv >> 1) * 64, c0 = (wv & 1) * 64;
    const size_t ra0 = (size_t)rows_s[ar] * 1024, ra1 = (size_t)rows_s[64 + ar] * 1024;

    f32x4 acc[4][4];
#pragma unroll
    for (int r = 0; r < 4; ++r)
#pragma unroll
        for (int c = 0; c < 4; ++c) acc[r][c] = 0.f;

    uint4 a0 = *(const uint4*)&ch[ra0 + kk];
    uint4 a1 = *(const uint4*)&ch[ra1 + kk];
    uint4 a2 = *(const uint4*)&cl[ra0 + kk];
    uint4 a3 = *(const uint4*)&cl[ra1 + kk];
    uint4 b0 = *(const uint4*)&wh[(size_t)(n0 + ar) * 1024 + kk];
    uint4 b1 = *(const uint4*)&wh[(size_t)(n0 + 64 + ar) * 1024 + kk];
    uint4 b2 = *(const uint4*)&wl[(size_t)(n0 + ar) * 1024 + kk];
    uint4 b3 = *(const uint4*)&wl[(size_t)(n0 + 64 + ar) * 1024 + kk];

    for (int it = 0; it < 32; ++it) {
        __syncthreads();
        *(uint4*)&sAh[aswz(ar, q)] = a0;
        *(uint4*)&sAh[aswz(64 + ar, q)] = a1;
        *(uint4*)&sAl[aswz(ar, q)] = a2;
        *(uint4*)&sAl[aswz(64 + ar, q)] = a3;
        {
            const int w0 = ar * 40 + kk, w1 = (64 + ar) * 40 + kk;
            *(uint4*)&sBh[w0] = b0; *(uint4*)&sBh[w1] = b1;
            *(uint4*)&sBl[w0] = b2; *(uint4*)&sBl[w1] = b3;
        }
        __syncthreads();
        if (it + 1 < 32) {
            const int k0 = (it + 1) * 32;
            a0 = *(const uint4*)&ch[ra0 + k0 + kk];
            a1 = *(const uint4*)&ch[ra1 + k0 + kk];
            a2 = *(const uint4*)&cl[ra0 + k0 + kk];
            a3 = *(const uint4*)&cl[ra1 + k0 + kk];
            b0 = *(const uint4*)&wh[(size_t)(n0 + ar) * 1024 + k0 + kk];
            b1 = *(const uint4*)&wh[(size_t)(n0 + 64 + ar) * 1024 + k0 + kk];
            b2 = *(const uint4*)&wl[(size_t)(n0 + ar) * 1024 + k0 + kk];
            b3 = *(const uint4*)&wl[(size_t)(n0 + 64 + ar) * 1024 + k0 + kk];
        }
        s16x8 fah[4], fal[4];
#pragma unroll
        for (int r = 0; r < 4; ++r) {
            const int base = aswz(r0 + r * 16 + ln, quad);
            fah[r] = *(const s16x8*)&sAh[base];
            fal[r] = *(const s16x8*)&sAl[base];
        }
#pragma unroll
        for (int c = 0; c < 4; ++c) {
            const int bb = (c0 + c * 16 + ln) * 40 + quad * 8;
            s16x8 fbh = *(const s16x8*)&sBh[bb];
            s16x8 fbl = *(const s16x8*)&sBl[bb];
#pragma unroll
            for (int r = 0; r < 4; ++r) {
                acc[r][c] = __builtin_amdgcn_mfma_f32_16x16x32_bf16(fah[r], fbh, acc[r][c], 0, 0, 0);
                acc[r][c] = __builtin_amdgcn_mfma_f32_16x16x32_bf16(fah[r], fbl, acc[r][c], 0, 0, 0);
                acc[r][c] = __builtin_amdgcn_mfma_f32_16x16x32_bf16(fal[r], fbh, acc[r][c], 0, 0, 0);
            }
        }
    }
#pragma unroll
    for (int c = 0; c < 4; ++c) {
        const int n = n0 + c0 + c * 16 + ln;
        const float bv = bias[n];
#pragma unroll
        for (int r = 0; r < 4; ++r)
#pragma unroll
            for (int g = 0; g < 4; ++g) {
                const int m = m0 + r0 + r * 16 + quad * 4 + g;
                const int b = m >> 11, t = m & 2047;
                const float mk0 = xm[(size_t)b * TT + 2 * t];
                const float mk1 = xm[(size_t)b * TT + 2 * t + 1];
                const float v = acc[r][c][g] + bv;
                float2 o2; o2.x = v * mk0; o2.y = v * mk1;
                *(float2*)&outp[((size_t)b * CIN + n) * TT + 2 * t] = o2;
            }
    }
}

// ================================ launch ===================================
extern "C" void kernel_launch(void* const* d_in, const int* in_sizes, int n_in,
                              void* d_out, int out_size, void* d_ws, size_t ws_size,
                              hipStream_t stream) {
    const float* x  = (const float*)d_in[0];
    const float* xm = (const float*)d_in[1];
    const float* wi = (const float*)d_in[2];
    const float* bi = (const float*)d_in[3];
    const float* cb = (const float*)d_in[4];
    const float* wo = (const float*)d_in[5];
    const float* bo = (const float*)d_in[6];

    float* outp     = (float*)d_out;
    float* idx_out  = outp + (size_t)NB * CIN * TT;   // offset 33,554,432 floats
    float* loss_out = idx_out + MM;
    // scratch inside d_out's 128 MB out-region (dead before k_out rewrites it):
    // xt f32 (64 MB) + xthi (32 MB) + xtlo (32 MB) = exactly 128 MB.
    float* xt  = outp;
    short* xth = (short*)(outp + 16777216);
    short* xtl = xth + 16777216;

    char* p = (char*)d_ws;   // base ~28.2 MB (R1 proved >=65 MB safe)
    short* wih = (short*)p; p += (size_t)CIN * 2048 * 2;
    short* wim = (short*)p; p += (size_t)CIN * 2048 * 2;
    short* wil = (short*)p; p += (size_t)CIN * 2048 * 2;
    short* cbh = (short*)p; p += (size_t)KC * DVQ * 2;
    short* cbl = (short*)p; p += (size_t)KC * DVQ * 2;
    short* woh = (short*)p; p += (size_t)CIN * DVQ * 2;
    short* wol = (short*)p; p += (size_t)CIN * DVQ * 2;
    float*  c32 = (float*)p;  p += KC * sizeof(float);
    double* c64 = (double*)p; p += KC * sizeof(double);
    float4* pb  = (float4*)p; p += (size_t)16 * MM * sizeof(float4);
    float* partials = (float*)p; p += MM * sizeof(float);
    int*   idxbuf   = (int*)p;   p += MM * sizeof(int);
    // optional fast-path A-planes: 3 x 64 MB right after the base layout
    short* Ah = (short*)p; p += (size_t)MM * 2048 * 2;
    short* Am = (short*)p; p += (size_t)MM * 2048 * 2;
    short* Al = (short*)p; p += (size_t)MM * 2048 * 2;
    const size_t need = (size_t)(p - (char*)d_ws);    // ~220.2 MB
    const bool fast = ws_size >= need;

    dim3 blk(256);
    k_split3<<<dim3(2048), blk, 0, stream>>>(wi, wih, wim, wil, CIN * 2048 / 4);
    k_split2<<<dim3(2048), blk, 0, stream>>>(cb, cbh, cbl, KC * DVQ / 4);
    k_split2<<<dim3(1024), blk, 0, stream>>>(wo, woh, wol, CIN * DVQ / 4);
    k_cnorm <<<dim3(KC),   blk, 0, stream>>>(cb, c32, c64);
    if (fast) {
        k_asplit<<<dim3(1024), blk, 0, stream>>>(x, Ah, Am, Al);
        k_convp <<<dim3(1024), blk, 0, stream>>>(Ah, Am, Al, wih, wim, wil, bi, xt, xth, xtl);
    } else {
        k_conv  <<<dim3(2048), blk, 0, stream>>>(x, wih, wim, wil, bi, xt, xth, xtl);
    }
    k_dot   <<<dim3(16, 128), blk, 0, stream>>>(xth, xtl, cbh, cbl, c32, pb);
    k_pick  <<<dim3(MM / 4), blk, 0, stream>>>(pb, c64, xt, cb, idxbuf, idx_out);
    k_losspart<<<dim3(MM), blk, 0, stream>>>(xt, cb, idxbuf, partials);
    k_lossfinal<<<1, blk, 0, stream>>>(partials, loss_out);
    k_out   <<<dim3(8, 128), blk, 0, stream>>>(idxbuf, cbh, cbl, woh, wol, bo, xm, outp);
}

// Round 2
// 1059.989 us; speedup vs baseline: 1.0814x; 1.0198x over previous
//
#include <hip/hip_runtime.h>

#define NB   8
#define CIN  1024
#define TT   4096
#define DVQ  1024
#define KC   2048
#define MM   16384

typedef short s16x8 __attribute__((ext_vector_type(8)));
typedef float f32x4 __attribute__((ext_vector_type(4)));

__device__ __forceinline__ short f2bf(float f) {
    unsigned u = __float_as_uint(f);
    u = u + 0x7fffu + ((u >> 16) & 1u);   // RNE
    return (short)(u >> 16);
}
__device__ __forceinline__ float bf2f(short h) {
    return __uint_as_float(((unsigned)(unsigned short)h) << 16);
}
__device__ __forceinline__ unsigned pk(short a, short b) {
    return (unsigned)(unsigned short)a | ((unsigned)(unsigned short)b << 16);
}
__device__ __forceinline__ void split3(float v, short& h, short& m, short& l) {
    h = f2bf(v); float r1 = v - bf2f(h);
    m = f2bf(r1); float r2 = r1 - bf2f(m);
    l = f2bf(r2);
}
// swizzled A-plane address (shorts): row-major, 40 shorts/row, 8-short blocks
// XOR-permuted by (row>>3)&3.  (legacy kernels)
__device__ __forceinline__ int aswz(int row, int q) {
    return row * 40 + (((q ^ (row >> 3)) & 3) << 3);
}
__device__ __forceinline__ bool lesskey(float v, int k, float v2, int k2) {
    return v < v2 || (v == v2 && k < k2);
}
__device__ __forceinline__ void merge2(float& b1, int& k1, float& b2, int& k2,
                                       float o1, int ok1, float o2, int ok2) {
    if (lesskey(o1, ok1, b1, k1)) {
        float nb2; int nk2;
        if (lesskey(b1, k1, o2, ok2)) { nb2 = b1; nk2 = k1; } else { nb2 = o2; nk2 = ok2; }
        b1 = o1; k1 = ok1; b2 = nb2; k2 = nk2;
    } else if (lesskey(o1, ok1, b2, k2)) {
        b2 = o1; k2 = ok1;
    }
}
// async 16B global->LDS copy (direct-to-shared DMA)
__device__ __forceinline__ void gload16(void* lds, const void* g) {
    __builtin_amdgcn_global_load_lds((const __attribute__((address_space(1))) void*)g,
                                     (__attribute__((address_space(3))) void*)lds, 16, 0, 0);
}

// ============================= preps =======================================
__global__ __launch_bounds__(256) void k_split3(const float* __restrict__ src,
                                                short* __restrict__ h, short* __restrict__ m,
                                                short* __restrict__ l, int n4) {
    int i = blockIdx.x * 256 + threadIdx.x;
    if (i >= n4) return;
    float4 v = ((const float4*)src)[i];
    short4 H, M, L;
    split3(v.x, H.x, M.x, L.x); split3(v.y, H.y, M.y, L.y);
    split3(v.z, H.z, M.z, L.z); split3(v.w, H.w, M.w, L.w);
    ((short4*)h)[i] = H; ((short4*)m)[i] = M; ((short4*)l)[i] = L;
}

__global__ __launch_bounds__(256) void k_split2(const float* __restrict__ src,
                                                short* __restrict__ h, short* __restrict__ l, int n4) {
    int i = blockIdx.x * 256 + threadIdx.x;
    if (i >= n4) return;
    float4 v = ((const float4*)src)[i];
    short4 H, L;
    H.x = f2bf(v.x); L.x = f2bf(v.x - bf2f(H.x));
    H.y = f2bf(v.y); L.y = f2bf(v.y - bf2f(H.y));
    H.z = f2bf(v.z); L.z = f2bf(v.z - bf2f(H.z));
    H.w = f2bf(v.w); L.w = f2bf(v.w - bf2f(H.w));
    ((short4*)h)[i] = H; ((short4*)l)[i] = L;
}

__global__ __launch_bounds__(256) void k_cnorm(const float* __restrict__ cb,
                                               float* __restrict__ c32,
                                               double* __restrict__ c64) {
    __shared__ double red[256];
    const float* row = cb + (size_t)blockIdx.x * DVQ;
    float4 v = ((const float4*)row)[threadIdx.x];
    red[threadIdx.x] = (double)v.x * v.x + (double)v.y * v.y +
                       (double)v.z * v.z + (double)v.w * v.w;
    __syncthreads();
    for (int o = 128; o > 0; o >>= 1) {
        if (threadIdx.x < o) red[threadIdx.x] += red[threadIdx.x + o];
        __syncthreads();
    }
    if (threadIdx.x == 0) { c64[blockIdx.x] = red[0]; c32[blockIdx.x] = (float)red[0]; }
}

// ============ A-plane materialization: transpose + 3-way RNE split =========
__global__ __launch_bounds__(256) void k_asplit(const float* __restrict__ x,
                                                short* __restrict__ ah,
                                                short* __restrict__ am,
                                                short* __restrict__ al) {
    const int bid = blockIdx.x;
    const int b = bid >> 7, cblk = (bid >> 5) & 3, tch = bid & 31;
    const int c = cblk * 256 + threadIdx.x;
    const float* xr = x + ((size_t)b * CIN + c) * TT + tch * 128;
    unsigned* AH = (unsigned*)ah;
    unsigned* AM = (unsigned*)am;
    unsigned* AL = (unsigned*)al;
    const int mbase = b * 2048 + tch * 64;
#pragma unroll 4
    for (int i = 0; i < 32; ++i) {
        float4 v = *(const float4*)(xr + 4 * i);
        short h0, mm0, l0, h1, mm1, l1, h2, mm2, l2, h3, mm3, l3;
        split3(v.x, h0, mm0, l0); split3(v.y, h1, mm1, l1);
        split3(v.z, h2, mm2, l2); split3(v.w, h3, mm3, l3);
        const size_t o0 = (size_t)(mbase + 2 * i) * 1024 + c;
        const size_t o1 = o0 + 1024;
        AH[o0] = pk(h0, h1); AM[o0] = pk(mm0, mm1); AL[o0] = pk(l0, l1);
        AH[o1] = pk(h2, h3); AM[o1] = pk(mm2, mm3); AL[o1] = pk(l2, l3);
    }
}

// ======== conv-in GEMM from materialized planes (fast path) ================
// 128x128 tile, BK=32, 4 waves (2x2), wave tile 64x64.  global_load_lds 16B
// staging into a 16B-block XOR-swizzled LDS layout: logical (row,q) stored at
// physical (row, q ^ ((row>>1)&3)).  Since global_load_lds writes linearly
// (uniform base + lane*16), the swizzle is applied by permuting the per-lane
// GLOBAL source column (rule #21: both-sides-or-neither), and the same XOR on
// the ds_read offsets.  Fragment reads drop from 8-way to 2-way (free) bank
// aliasing.  Same 6 products in the same order + same K=64 chunk flush =>
// bit-identical numerics.
__global__ __launch_bounds__(256, 2) void k_convp(const short* __restrict__ ah,
                                                  const short* __restrict__ am,
                                                  const short* __restrict__ al,
                                                  const short* __restrict__ wh,
                                                  const short* __restrict__ wm,
                                                  const short* __restrict__ wl,
                                                  const float* __restrict__ bias,
                                                  float* __restrict__ xt,
                                                  short* __restrict__ xth,
                                                  short* __restrict__ xtl) {
    __shared__ short s[6][128 * 32];   // Ah Am Al Bh Bm Bl : 48 KiB
    const int tid = threadIdx.x;
    // XCD-aware remap: XCD cx owns 16 consecutive m-tiles x all 8 n-tiles
    const int lin = blockIdx.x;
    const int cx = lin & 7, j = lin >> 3;
    const int m0 = (cx * 16 + (j >> 3)) * 128;
    const int n0 = (j & 7) * 128;

    const int wv = tid >> 6, lane = tid & 63;
    const int slot0 = wv * 128 + lane, slot1 = slot0 + 64;   // 512 slots/plane
    // physical slot (row, qp) receives logical (row, qp ^ ((row>>1)&3))
    const int row0 = slot0 >> 2, c80 = ((slot0 & 3) ^ ((slot0 >> 3) & 3)) * 8;
    const int row1 = slot1 >> 2, c81 = ((slot1 & 3) ^ ((slot1 >> 3) & 3)) * 8;
    const size_t ga0 = (size_t)(m0 + row0) * 2048 + c80;
    const size_t ga1 = (size_t)(m0 + row1) * 2048 + c81;
    const size_t gb0 = (size_t)(n0 + row0) * 2048 + c80;
    const size_t gb1 = (size_t)(n0 + row1) * 2048 + c81;

    const int ln = tid & 15, quad = (tid >> 4) & 3;
    const int qsw = (quad ^ ((ln >> 1) & 3)) * 8;   // swizzled 16B block col
    const int r0w = (wv >> 1) * 64, c0w = (wv & 1) * 64;

    f32x4 acc[4][4], sums[4][4];
#pragma unroll
    for (int r = 0; r < 4; ++r)
#pragma unroll
        for (int c = 0; c < 4; ++c) { acc[r][c] = 0.f; sums[r][c] = 0.f; }

#pragma unroll 2
    for (int it = 0; it < 64; ++it) {
        const int k0 = it * 32;
        __syncthreads();                       // prior reads of buffer done
        gload16(&s[0][slot0 * 8], ah + ga0 + k0);
        gload16(&s[0][slot1 * 8], ah + ga1 + k0);
        gload16(&s[1][slot0 * 8], am + ga0 + k0);
        gload16(&s[1][slot1 * 8], am + ga1 + k0);
        gload16(&s[2][slot0 * 8], al + ga0 + k0);
        gload16(&s[2][slot1 * 8], al + ga1 + k0);
        gload16(&s[3][slot0 * 8], wh + gb0 + k0);
        gload16(&s[3][slot1 * 8], wh + gb1 + k0);
        gload16(&s[4][slot0 * 8], wm + gb0 + k0);
        gload16(&s[4][slot1 * 8], wm + gb1 + k0);
        gload16(&s[5][slot0 * 8], wl + gb0 + k0);
        gload16(&s[5][slot1 * 8], wl + gb1 + k0);
        __syncthreads();                       // vmcnt(0) drain + barrier

        s16x8 fa0[4], fa1[4], fa2[4];          // hold A frags, stream B
#pragma unroll
        for (int r = 0; r < 4; ++r) {
            const int off = (r0w + r * 16 + ln) * 32 + qsw;
            fa0[r] = *(const s16x8*)&s[0][off];
            fa1[r] = *(const s16x8*)&s[1][off];
            fa2[r] = *(const s16x8*)&s[2][off];
        }
#pragma unroll
        for (int c = 0; c < 4; ++c) {
            const int boff = (c0w + c * 16 + ln) * 32 + qsw;
            s16x8 fbh = *(const s16x8*)&s[3][boff];
            s16x8 fbm = *(const s16x8*)&s[4][boff];
            s16x8 fbl = *(const s16x8*)&s[5][boff];
#pragma unroll
            for (int r = 0; r < 4; ++r) {
                acc[r][c] = __builtin_amdgcn_mfma_f32_16x16x32_bf16(fa0[r], fbh, acc[r][c], 0, 0, 0);
                acc[r][c] = __builtin_amdgcn_mfma_f32_16x16x32_bf16(fa0[r], fbm, acc[r][c], 0, 0, 0);
                acc[r][c] = __builtin_amdgcn_mfma_f32_16x16x32_bf16(fa1[r], fbh, acc[r][c], 0, 0, 0);
                acc[r][c] = __builtin_amdgcn_mfma_f32_16x16x32_bf16(fa0[r], fbl, acc[r][c], 0, 0, 0);
                acc[r][c] = __builtin_amdgcn_mfma_f32_16x16x32_bf16(fa1[r], fbm, acc[r][c], 0, 0, 0);
                acc[r][c] = __builtin_amdgcn_mfma_f32_16x16x32_bf16(fa2[r], fbh, acc[r][c], 0, 0, 0);
            }
        }
        if (it & 1) {   // chunk flush (K=64) — identical to legacy
#pragma unroll
            for (int r = 0; r < 4; ++r)
#pragma unroll
                for (int c = 0; c < 4; ++c) { sums[r][c] += acc[r][c]; acc[r][c] = 0.f; }
        }
    }
#pragma unroll
    for (int c = 0; c < 4; ++c) {
        const int n = n0 + c0w + c * 16 + ln;
        const float bv = bias[n];
#pragma unroll
        for (int r = 0; r < 4; ++r)
#pragma unroll
            for (int g = 0; g < 4; ++g) {
                const int m = m0 + r0w + r * 16 + quad * 4 + g;
                const float v = sums[r][c][g] + bv;
                const size_t o = (size_t)m * DVQ + n;
                xt[o] = v;
                short h = f2bf(v);
                xth[o] = h;
                xtl[o] = f2bf(v - bf2f(h));
            }
    }
}

// ======== conv-in GEMM: legacy in-kernel split (ws fallback) ===============
__global__ __launch_bounds__(256, 2) void k_conv(const float* __restrict__ x,
                                                 const short* __restrict__ wh,
                                                 const short* __restrict__ wm,
                                                 const short* __restrict__ wl,
                                                 const float* __restrict__ bias,
                                                 float* __restrict__ xt,
                                                 short* __restrict__ xth,
                                                 short* __restrict__ xtl) {
    __shared__ short sAh[128 * 40], sAm[128 * 40], sAl[128 * 40];
    __shared__ short sBh[64 * 40],  sBm[64 * 40],  sBl[64 * 40];
    const int tid = threadIdx.x;
    const int lin = blockIdx.x;
    const int cx = lin & 7, j = lin >> 3;
    const int m0 = (cx * 16 + (j >> 4)) * 128;
    const int n0 = (j & 15) * 64;
    const int b = m0 >> 11, t0 = m0 & 2047;
    const float* xb = x + (size_t)b * CIN * TT + 2 * t0;

    const int aw = tid >> 6, p = tid & 63;
    const int brow = tid >> 2, bq = tid & 3;
    const int ln = tid & 15, quad = (tid >> 4) & 3;
    const int r0 = (aw >> 1) * 64, c0 = (aw & 1) * 32;

    f32x4 acc[4][2], sums[4][2];
#pragma unroll
    for (int r = 0; r < 4; ++r)
#pragma unroll
        for (int c = 0; c < 2; ++c) { acc[r][c] = 0.f; sums[r][c] = 0.f; }

    float4 av[4];
    uint4 bh0, bm0, bl0;
#pragma unroll
    for (int r = 0; r < 4; ++r) av[r] = *(const float4*)(xb + (size_t)(4 * r + aw) * TT + 4 * p);
    {
        const size_t o = (size_t)(n0 + brow) * 2048 + bq * 8;
        bh0 = *(const uint4*)&wh[o]; bm0 = *(const uint4*)&wm[o]; bl0 = *(const uint4*)&wl[o];
    }

    for (int it = 0; it < 64; ++it) {
        __syncthreads();
#pragma unroll
        for (int r = 0; r < 4; ++r) {
            const int ii = r * 4 + aw;
            const int q = ii >> 2, off = (2 * ii) & 7;
            const int a0 = aswz(2 * p, q) + off;
            const int a1 = aswz(2 * p + 1, q) + off;
            float4 v = av[r];
            short hx, mx, lx, hy, my, ly;
            split3(v.x, hx, mx, lx); split3(v.y, hy, my, ly);
            *(unsigned*)&sAh[a0] = pk(hx, hy);
            *(unsigned*)&sAm[a0] = pk(mx, my);
            *(unsigned*)&sAl[a0] = pk(lx, ly);
            split3(v.z, hx, mx, lx); split3(v.w, hy, my, ly);
            *(unsigned*)&sAh[a1] = pk(hx, hy);
            *(unsigned*)&sAm[a1] = pk(mx, my);
            *(unsigned*)&sAl[a1] = pk(lx, ly);
        }
        {
            const int w0 = brow * 40 + bq * 8;
            *(uint4*)&sBh[w0] = bh0; *(uint4*)&sBm[w0] = bm0; *(uint4*)&sBl[w0] = bl0;
        }
        __syncthreads();
        if (it + 1 < 64) {
            const int i0 = (it + 1) * 16, k0 = (it + 1) * 32;
#pragma unroll
            for (int r = 0; r < 4; ++r)
                av[r] = *(const float4*)(xb + (size_t)(i0 + 4 * r + aw) * TT + 4 * p);
            const size_t o = (size_t)(n0 + brow) * 2048 + k0 + bq * 8;
            bh0 = *(const uint4*)&wh[o]; bm0 = *(const uint4*)&wm[o]; bl0 = *(const uint4*)&wl[o];
        }
        s16x8 fah[4], fam[4], fal[4];
#pragma unroll
        for (int r = 0; r < 4; ++r) {
            const int base = aswz(r0 + r * 16 + ln, quad);
            fah[r] = *(const s16x8*)&sAh[base];
            fam[r] = *(const s16x8*)&sAm[base];
            fal[r] = *(const s16x8*)&sAl[base];
        }
#pragma unroll
        for (int c = 0; c < 2; ++c) {
            const int bb = (c0 + c * 16 + ln) * 40 + quad * 8;
            s16x8 fbh = *(const s16x8*)&sBh[bb];
            s16x8 fbm = *(const s16x8*)&sBm[bb];
            s16x8 fbl = *(const s16x8*)&sBl[bb];
#pragma unroll
            for (int r = 0; r < 4; ++r) {
                acc[r][c] = __builtin_amdgcn_mfma_f32_16x16x32_bf16(fah[r], fbh, acc[r][c], 0, 0, 0);
                acc[r][c] = __builtin_amdgcn_mfma_f32_16x16x32_bf16(fah[r], fbm, acc[r][c], 0, 0, 0);
                acc[r][c] = __builtin_amdgcn_mfma_f32_16x16x32_bf16(fam[r], fbh, acc[r][c], 0, 0, 0);
                acc[r][c] = __builtin_amdgcn_mfma_f32_16x16x32_bf16(fah[r], fbl, acc[r][c], 0, 0, 0);
                acc[r][c] = __builtin_amdgcn_mfma_f32_16x16x32_bf16(fam[r], fbm, acc[r][c], 0, 0, 0);
                acc[r][c] = __builtin_amdgcn_mfma_f32_16x16x32_bf16(fal[r], fbh, acc[r][c], 0, 0, 0);
            }
        }
        if (it & 1) {
#pragma unroll
            for (int r = 0; r < 4; ++r)
#pragma unroll
                for (int c = 0; c < 2; ++c) { sums[r][c] += acc[r][c]; acc[r][c] = 0.f; }
        }
    }
#pragma unroll
    for (int c = 0; c < 2; ++c) {
        const int n = n0 + c0 + c * 16 + ln;
        const float bv = bias[n];
#pragma unroll
        for (int r = 0; r < 4; ++r)
#pragma unroll
            for (int g = 0; g < 4; ++g) {
                const int m = m0 + r0 + r * 16 + quad * 4 + g;
                const float v = sums[r][c][g] + bv;
                const size_t o = (size_t)m * DVQ + n;
                xt[o] = v;
                short h = f2bf(v);
                xth[o] = h;
                xtl[o] = f2bf(v - bf2f(h));
            }
    }
}

// ====== distance GEMM (2-plane planes from conv) + fused exact top-2 =======
__global__ __launch_bounds__(256, 2) void k_dot(const short* __restrict__ xth,
                                                const short* __restrict__ xtl,
                                                const short* __restrict__ cbh,
                                                const short* __restrict__ cbl,
                                                const float* __restrict__ c32,
                                                float4* __restrict__ pb) {
    __shared__ __align__(16) short sAh[128 * 40], sAl[128 * 40], sBh[128 * 40], sBl[128 * 40];
    const int tid = threadIdx.x;
    const int n0 = blockIdx.x * 128, m0 = blockIdx.y * 128;
    const int ar = tid >> 2, q = tid & 3, kk = q * 8;
    const int ln = tid & 15, quad = (tid >> 4) & 3, wv = tid >> 6;
    const int r0 = (wv >> 1) * 64, c0 = (wv & 1) * 64;

    f32x4 acc[4][4];
#pragma unroll
    for (int r = 0; r < 4; ++r)
#pragma unroll
        for (int c = 0; c < 4; ++c) acc[r][c] = 0.f;

    uint4 a0 = *(const uint4*)&xth[(size_t)(m0 + ar) * 1024 + kk];
    uint4 a1 = *(const uint4*)&xth[(size_t)(m0 + 64 + ar) * 1024 + kk];
    uint4 a2 = *(const uint4*)&xtl[(size_t)(m0 + ar) * 1024 + kk];
    uint4 a3 = *(const uint4*)&xtl[(size_t)(m0 + 64 + ar) * 1024 + kk];
    uint4 b0 = *(const uint4*)&cbh[(size_t)(n0 + ar) * 1024 + kk];
    uint4 b1 = *(const uint4*)&cbh[(size_t)(n0 + 64 + ar) * 1024 + kk];
    uint4 b2 = *(const uint4*)&cbl[(size_t)(n0 + ar) * 1024 + kk];
    uint4 b3 = *(const uint4*)&cbl[(size_t)(n0 + 64 + ar) * 1024 + kk];

    for (int it = 0; it < 32; ++it) {
        __syncthreads();
        *(uint4*)&sAh[aswz(ar, q)] = a0;
        *(uint4*)&sAh[aswz(64 + ar, q)] = a1;
        *(uint4*)&sAl[aswz(ar, q)] = a2;
        *(uint4*)&sAl[aswz(64 + ar, q)] = a3;
        {
            const int w0 = ar * 40 + kk, w1 = (64 + ar) * 40 + kk;
            *(uint4*)&sBh[w0] = b0; *(uint4*)&sBh[w1] = b1;
            *(uint4*)&sBl[w0] = b2; *(uint4*)&sBl[w1] = b3;
        }
        __syncthreads();
        if (it + 1 < 32) {
            const int k0 = (it + 1) * 32;
            a0 = *(const uint4*)&xth[(size_t)(m0 + ar) * 1024 + k0 + kk];
            a1 = *(const uint4*)&xth[(size_t)(m0 + 64 + ar) * 1024 + k0 + kk];
            a2 = *(const uint4*)&xtl[(size_t)(m0 + ar) * 1024 + k0 + kk];
            a3 = *(const uint4*)&xtl[(size_t)(m0 + 64 + ar) * 1024 + k0 + kk];
            b0 = *(const uint4*)&cbh[(size_t)(n0 + ar) * 1024 + k0 + kk];
            b1 = *(const uint4*)&cbh[(size_t)(n0 + 64 + ar) * 1024 + k0 + kk];
            b2 = *(const uint4*)&cbl[(size_t)(n0 + ar) * 1024 + k0 + kk];
            b3 = *(const uint4*)&cbl[(size_t)(n0 + 64 + ar) * 1024 + k0 + kk];
        }
        s16x8 fah[4], fal[4];
#pragma unroll
        for (int r = 0; r < 4; ++r) {
            const int base = aswz(r0 + r * 16 + ln, quad);
            fah[r] = *(const s16x8*)&sAh[base];
            fal[r] = *(const s16x8*)&sAl[base];
        }
#pragma unroll
        for (int c = 0; c < 4; ++c) {
            const int bb = (c0 + c * 16 + ln) * 40 + quad * 8;
            s16x8 fbh = *(const s16x8*)&sBh[bb];
            s16x8 fbl = *(const s16x8*)&sBl[bb];
#pragma unroll
            for (int r = 0; r < 4; ++r) {
                acc[r][c] = __builtin_amdgcn_mfma_f32_16x16x32_bf16(fah[r], fbh, acc[r][c], 0, 0, 0);
                acc[r][c] = __builtin_amdgcn_mfma_f32_16x16x32_bf16(fah[r], fbl, acc[r][c], 0, 0, 0);
                acc[r][c] = __builtin_amdgcn_mfma_f32_16x16x32_bf16(fal[r], fbh, acc[r][c], 0, 0, 0);
            }
        }
    }
    // per-thread top-2 (ascending n per row; strict < keeps first occurrence)
    float tb1[16], tb2[16]; int tk1[16], tk2[16];
#pragma unroll
    for (int i = 0; i < 16; ++i) { tb1[i] = INFINITY; tb2[i] = INFINITY; tk1[i] = 0; tk2[i] = 0; }
#pragma unroll
    for (int c = 0; c < 4; ++c) {
        const int n = n0 + c0 + c * 16 + ln;
        const float cn = c32[n];
#pragma unroll
        for (int r = 0; r < 4; ++r)
#pragma unroll
            for (int g = 0; g < 4; ++g) {
                const float s = cn - 2.0f * acc[r][c][g];
                const int i = r * 4 + g;
                if (s < tb1[i]) { tb2[i] = tb1[i]; tk2[i] = tk1[i]; tb1[i] = s; tk1[i] = n; }
                else if (s < tb2[i]) { tb2[i] = s; tk2[i] = n; }
            }
    }
    // lossless top-2 butterfly across the 16 ln-lanes
#pragma unroll
    for (int off = 1; off < 16; off <<= 1) {
#pragma unroll
        for (int i = 0; i < 16; ++i) {
            float o1 = __shfl_xor(tb1[i], off); int ok1 = __shfl_xor(tk1[i], off);
            float o2 = __shfl_xor(tb2[i], off); int ok2 = __shfl_xor(tk2[i], off);
            merge2(tb1[i], tk1[i], tb2[i], tk2[i], o1, ok1, o2, ok2);
        }
    }
    __syncthreads();
    float4* part = (float4*)sAh;   // 4 KB overlay
    if (ln == 0) {
#pragma unroll
        for (int i = 0; i < 16; ++i) {
            const int lr = (i >> 2) * 16 + quad * 4 + (i & 3);
            float4 v; v.x = tb1[i]; v.y = tb2[i];
            v.z = __int_as_float(tk1[i]); v.w = __int_as_float(tk2[i]);
            part[wv * 64 + lr] = v;
        }
    }
    __syncthreads();
    if (tid < 128) {
        const int row = tid, h = row >> 6, lr = row & 63;
        float4 A = part[(2 * h) * 64 + lr];
        float4 B = part[(2 * h + 1) * 64 + lr];
        float b1v = A.x, b2v = A.y; int k1 = __float_as_int(A.z), k2 = __float_as_int(A.w);
        merge2(b1v, k1, b2v, k2, B.x, __float_as_int(B.z), B.y, __float_as_int(B.w));
        float4 o; o.x = b1v; o.y = b2v; o.z = __int_as_float(k1); o.w = __int_as_float(k2);
        pb[(size_t)blockIdx.x * MM + m0 + row] = o;
    }
}

// ============ merge 16 strips + exact f64 rescore of top-2 =================
__global__ __launch_bounds__(256) void k_pick(const float4* __restrict__ pb,
                                              const double* __restrict__ c64,
                                              const float* __restrict__ xt,
                                              const float* __restrict__ cb,
                                              int* __restrict__ idxbuf,
                                              float* __restrict__ idx_out) {
    const int wv = threadIdx.x >> 6, lane = threadIdx.x & 63;
    const int m = blockIdx.x * 4 + wv;
    float4 P = pb[m];
    float b1 = P.x, b2 = P.y; int k1 = __float_as_int(P.z), k2 = __float_as_int(P.w);
#pragma unroll
    for (int s = 1; s < 16; ++s) {
        float4 Q = pb[(size_t)s * MM + m];
        merge2(b1, k1, b2, k2, Q.x, __float_as_int(Q.z), Q.y, __float_as_int(Q.w));
    }
    const float* xr = xt + (size_t)m * DVQ;
    const float* c1 = cb + (size_t)k1 * DVQ;
    const float* c2 = cb + (size_t)k2 * DVQ;
    double e1 = 0.0, e2 = 0.0;
    for (int j = 0; j < DVQ / 64; ++j) {
        const int d = j * 64 + lane;
        const double xv = xr[d];
        e1 += xv * (double)c1[d]; e2 += xv * (double)c2[d];
    }
    for (int off = 32; off > 0; off >>= 1) { e1 += __shfl_xor(e1, off); e2 += __shfl_xor(e2, off); }
    if (lane == 0) {
        const double s1 = c64[k1] - 2.0 * e1;
        const double s2 = c64[k2] - 2.0 * e2;
        const int kf = (s2 < s1 || (s2 == s1 && k2 < k1)) ? k2 : k1;
        idxbuf[m] = kf;
        idx_out[m] = (float)kf;
    }
}

// ================================= loss ====================================
__global__ __launch_bounds__(256) void k_losspart(const float* __restrict__ xt,
                                                  const float* __restrict__ cb,
                                                  const int* __restrict__ idxbuf,
                                                  float* __restrict__ partials) {
    __shared__ float red[256];
    const int m = blockIdx.x;
    const int row = idxbuf[m];
    float4 a = ((const float4*)(xt + (size_t)m * DVQ))[threadIdx.x];
    float4 c = ((const float4*)(cb + (size_t)row * DVQ))[threadIdx.x];
    const float dx = a.x - c.x, dy = a.y - c.y, dz = a.z - c.z, dw = a.w - c.w;
    red[threadIdx.x] = dx * dx + dy * dy + dz * dz + dw * dw;
    __syncthreads();
    for (int o = 128; o > 0; o >>= 1) {
        if (threadIdx.x < o) red[threadIdx.x] += red[threadIdx.x + o];
        __syncthreads();
    }
    if (threadIdx.x == 0) partials[m] = red[0];
}

__global__ __launch_bounds__(256) void k_lossfinal(const float* __restrict__ partials,
                                                   float* __restrict__ loss_out) {
    __shared__ float red[256];
    float s = 0.0f;
    for (int i = threadIdx.x; i < MM; i += 256) s += partials[i];
    red[threadIdx.x] = s;
    __syncthreads();
    for (int o = 128; o > 0; o >>= 1) {
        if (threadIdx.x < o) red[threadIdx.x] += red[threadIdx.x + o];
        __syncthreads();
    }
    if (threadIdx.x == 0) loss_out[0] = red[0] / (float)((size_t)MM * DVQ);
}

// ============== out projection (gathered codebook, 2-plane) ================
__global__ __launch_bounds__(256, 2) void k_out(const int* __restrict__ idxbuf,
                                                const short* __restrict__ ch,
                                                const short* __restrict__ cl,
                                                const short* __restrict__ wh,
                                                const short* __restrict__ wl,
                                                const float* __restrict__ bias,
                                                const float* __restrict__ xm,
                                                float* __restrict__ outp) {
    __shared__ short sAh[128 * 40], sAl[128 * 40], sBh[128 * 40], sBl[128 * 40];
    __shared__ int rows_s[128];
    const int tid = threadIdx.x;
    const int m0 = blockIdx.y * 128, n0 = blockIdx.x * 128;
    if (tid < 128) rows_s[tid] = idxbuf[m0 + tid];
    __syncthreads();
    const int ar = tid >> 2, q = tid & 3, kk = q * 8;
    const int ln = tid & 15, quad = (tid >> 4) & 3, wv = tid >> 6;
    const int r0 = (wv >> 1) * 64, c0 = (wv & 1) * 64;
    const size_t ra0 = (size_t)rows_s[ar] * 1024, ra1 = (size_t)rows_s[64 + ar] * 1024;

    f32x4 acc[4][4];
#pragma unroll
    for (int r = 0; r < 4; ++r)
#pragma unroll
        for (int c = 0; c < 4; ++c) acc[r][c] = 0.f;

    uint4 a0 = *(const uint4*)&ch[ra0 + kk];
    uint4 a1 = *(const uint4*)&ch[ra1 + kk];
    uint4 a2 = *(const uint4*)&cl[ra0 + kk];
    uint4 a3 = *(const uint4*)&cl[ra1 + kk];
    uint4 b0 = *(const uint4*)&wh[(size_t)(n0 + ar) * 1024 + kk];
    uint4 b1 = *(const uint4*)&wh[(size_t)(n0 + 64 + ar) * 1024 + kk];
    uint4 b2 = *(const uint4*)&wl[(size_t)(n0 + ar) * 1024 + kk];
    uint4 b3 = *(const uint4*)&wl[(size_t)(n0 + 64 + ar) * 1024 + kk];

    for (int it = 0; it < 32; ++it) {
        __syncthreads();
        *(uint4*)&sAh[aswz(ar, q)] = a0;
        *(uint4*)&sAh[aswz(64 + ar, q)] = a1;
        *(uint4*)&sAl[aswz(ar, q)] = a2;
        *(uint4*)&sAl[aswz(64 + ar, q)] = a3;
        {
            const int w0 = ar * 40 + kk, w1 = (64 + ar) * 40 + kk;
            *(uint4*)&sBh[w0] = b0; *(uint4*)&sBh[w1] = b1;
            *(uint4*)&sBl[w0] = b2; *(uint4*)&sBl[w1] = b3;
        }
        __syncthreads();
        if (it + 1 < 32) {
            const int k0 = (it + 1) * 32;
            a0 = *(const uint4*)&ch[ra0 + k0 + kk];
            a1 = *(const uint4*)&ch[ra1 + k0 + kk];
            a2 = *(const uint4*)&cl[ra0 + k0 + kk];
            a3 = *(const uint4*)&cl[ra1 + k0 + kk];
            b0 = *(const uint4*)&wh[(size_t)(n0 + ar) * 1024 + k0 + kk];
            b1 = *(const uint4*)&wh[(size_t)(n0 + 64 + ar) * 1024 + k0 + kk];
            b2 = *(const uint4*)&wl[(size_t)(n0 + ar) * 1024 + k0 + kk];
            b3 = *(const uint4*)&wl[(size_t)(n0 + 64 + ar) * 1024 + k0 + kk];
        }
        s16x8 fah[4], fal[4];
#pragma unroll
        for (int r = 0; r < 4; ++r) {
            const int base = aswz(r0 + r * 16 + ln, quad);
            fah[r] = *(const s16x8*)&sAh[base];
            fal[r] = *(const s16x8*)&sAl[base];
        }
#pragma unroll
        for (int c = 0; c < 4; ++c) {
            const int bb = (c0 + c * 16 + ln) * 40 + quad * 8;
            s16x8 fbh = *(const s16x8*)&sBh[bb];
            s16x8 fbl = *(const s16x8*)&sBl[bb];
#pragma unroll
            for (int r = 0; r < 4; ++r) {
                acc[r][c] = __builtin_amdgcn_mfma_f32_16x16x32_bf16(fah[r], fbh, acc[r][c], 0, 0, 0);
                acc[r][c] = __builtin_amdgcn_mfma_f32_16x16x32_bf16(fah[r], fbl, acc[r][c], 0, 0, 0);
                acc[r][c] = __builtin_amdgcn_mfma_f32_16x16x32_bf16(fal[r], fbh, acc[r][c], 0, 0, 0);
            }
        }
    }
#pragma unroll
    for (int c = 0; c < 4; ++c) {
        const int n = n0 + c0 + c * 16 + ln;
        const float bv = bias[n];
#pragma unroll
        for (int r = 0; r < 4; ++r)
#pragma unroll
            for (int g = 0; g < 4; ++g) {
                const int m = m0 + r0 + r * 16 + quad * 4 + g;
                const int b = m >> 11, t = m & 2047;
                const float mk0 = xm[(size_t)b * TT + 2 * t];
                const float mk1 = xm[(size_t)b * TT + 2 * t + 1];
                const float v = acc[r][c][g] + bv;
                float2 o2; o2.x = v * mk0; o2.y = v * mk1;
                *(float2*)&outp[((size_t)b * CIN + n) * TT + 2 * t] = o2;
            }
    }
}

// ================================ launch ===================================
extern "C" void kernel_launch(void* const* d_in, const int* in_sizes, int n_in,
                              void* d_out, int out_size, void* d_ws, size_t ws_size,
                              hipStream_t stream) {
    const float* x  = (const float*)d_in[0];
    const float* xm = (const float*)d_in[1];
    const float* wi = (const float*)d_in[2];
    const float* bi = (const float*)d_in[3];
    const float* cb = (const float*)d_in[4];
    const float* wo = (const float*)d_in[5];
    const float* bo = (const float*)d_in[6];

    float* outp     = (float*)d_out;
    float* idx_out  = outp + (size_t)NB * CIN * TT;   // offset 33,554,432 floats
    float* loss_out = idx_out + MM;
    // scratch inside d_out's 128 MB out-region (dead before k_out rewrites it):
    // xt f32 (64 MB) + xthi (32 MB) + xtlo (32 MB) = exactly 128 MB.
    float* xt  = outp;
    short* xth = (short*)(outp + 16777216);
    short* xtl = xth + 16777216;

    char* p = (char*)d_ws;   // base ~28.2 MB (R1 proved >=65 MB safe)
    short* wih = (short*)p; p += (size_t)CIN * 2048 * 2;
    short* wim = (short*)p; p += (size_t)CIN * 2048 * 2;
    short* wil = (short*)p; p += (size_t)CIN * 2048 * 2;
    short* cbh = (short*)p; p += (size_t)KC * DVQ * 2;
    short* cbl = (short*)p; p += (size_t)KC * DVQ * 2;
    short* woh = (short*)p; p += (size_t)CIN * DVQ * 2;
    short* wol = (short*)p; p += (size_t)CIN * DVQ * 2;
    float*  c32 = (float*)p;  p += KC * sizeof(float);
    double* c64 = (double*)p; p += KC * sizeof(double);
    float4* pb  = (float4*)p; p += (size_t)16 * MM * sizeof(float4);
    float* partials = (float*)p; p += MM * sizeof(float);
    int*   idxbuf   = (int*)p;   p += MM * sizeof(int);
    // optional fast-path A-planes: 3 x 64 MB right after the base layout
    short* Ah = (short*)p; p += (size_t)MM * 2048 * 2;
    short* Am = (short*)p; p += (size_t)MM * 2048 * 2;
    short* Al = (short*)p; p += (size_t)MM * 2048 * 2;
    const size_t need = (size_t)(p - (char*)d_ws);    // ~220.2 MB
    const bool fast = ws_size >= need;

    dim3 blk(256);
    k_split3<<<dim3(2048), blk, 0, stream>>>(wi, wih, wim, wil, CIN * 2048 / 4);
    k_split2<<<dim3(2048), blk, 0, stream>>>(cb, cbh, cbl, KC * DVQ / 4);
    k_split2<<<dim3(1024), blk, 0, stream>>>(wo, woh, wol, CIN * DVQ / 4);
    k_cnorm <<<dim3(KC),   blk, 0, stream>>>(cb, c32, c64);
    if (fast) {
        k_asplit<<<dim3(1024), blk, 0, stream>>>(x, Ah, Am, Al);
        k_convp <<<dim3(1024), blk, 0, stream>>>(Ah, Am, Al, wih, wim, wil, bi, xt, xth, xtl);
    } else {
        k_conv  <<<dim3(2048), blk, 0, stream>>>(x, wih, wim, wil, bi, xt, xth, xtl);
    }
    k_dot   <<<dim3(16, 128), blk, 0, stream>>>(xth, xtl, cbh, cbl, c32, pb);
    k_pick  <<<dim3(MM / 4), blk, 0, stream>>>(pb, c64, xt, cb, idxbuf, idx_out);
    k_losspart<<<dim3(MM), blk, 0, stream>>>(xt, cb, idxbuf, partials);
    k_lossfinal<<<1, blk, 0, stream>>>(partials, loss_out);
    k_out   <<<dim3(8, 128), blk, 0, stream>>>(idxbuf, cbh, cbl, woh, wol, bo, xm, outp);
}